// Round 12
// baseline (211.920 us; speedup 1.0000x reference)
//
#include <hip/hip_runtime.h>
#include <stdint.h>

#define DEVI __device__ __forceinline__
typedef unsigned short u16;
typedef __attribute__((ext_vector_type(8))) short s16x8;
typedef __attribute__((ext_vector_type(4))) float f32x4;

typedef __attribute__((address_space(1))) void as1_void;
typedef __attribute__((address_space(3))) void as3_void;

DEVI u16 f2b(float f){
  union { float f; uint32_t u; } x; x.f = f;
  return (u16)((x.u + 0x7fffu + ((x.u >> 16) & 1u)) >> 16);
}
DEVI float b2f(u16 u){
  union { uint32_t u; float f; } x; x.u = ((uint32_t)u) << 16;
  return x.f;
}
DEVI void gload16(const void* g, void* l){
  __builtin_amdgcn_global_load_lds((as1_void*)g, (as3_void*)l, 16, 0, 0);
}
DEVI f32x4 MFMA(s16x8 a, s16x8 b, f32x4 c){
  return __builtin_amdgcn_mfma_f32_16x16x32_bf16(a, b, c, 0, 0, 0);
}

// ---------------- K0: all prep in ONE launch (16.6 KB LDS, high occ) --------
__global__ __launch_bounds__(256)
void k_prep(const float* __restrict__ Q, const float* __restrict__ Kc,
            const float* __restrict__ V,
            u16* __restrict__ Qb, u16* __restrict__ Kb, u16* __restrict__ Vb,
            const float* __restrict__ Wq, const float* __restrict__ Wk,
            const float* __restrict__ Wv, const float* __restrict__ Wo,
            u16* __restrict__ WqT, u16* __restrict__ WkT,
            u16* __restrict__ WvT, u16* __restrict__ WoT){
  __shared__ float t[64][65];
  const int bid = blockIdx.x, tid = threadIdx.x;
  if(bid < 12288){
    int tno = bid >> 12;
    int blk = bid & 4095;
    const float* s = (tno == 0) ? Q : (tno == 1) ? Kc : V;
    u16* d = (tno == 0) ? Qb : (tno == 1) ? Kb : Vb;
    int i = (blk * 256 + tid) * 4;
    float4 v = *(const float4*)(s + i);
    ushort4 o;
    o.x = f2b(v.x); o.y = f2b(v.y); o.z = f2b(v.z); o.w = f2b(v.w);
    *(ushort4*)(d + i) = o;
  } else {
    int j = bid - 12288;
    const float* src; u16* dst; int C, r0, c0;
    if(j < 768){
      int tno = j >> 8, rem = j & 255, head = rem >> 4, rt = rem & 15;
      src = ((tno == 0) ? Wq : (tno == 1) ? Wk : Wv) + head * 65536;
      dst = ((tno == 0) ? WqT : (tno == 1) ? WkT : WvT) + head * 65536;
      C = 64; r0 = rt * 64; c0 = 0;
    } else {
      int j2 = j - 768;
      src = Wo; dst = WoT; C = 1024;
      r0 = (j2 & 15) * 64; c0 = (j2 >> 4) * 64;
    }
    int tx = tid & 63, ty = tid >> 6;
    #pragma unroll
    for(int i2 = 0; i2 < 64; i2 += 4)
      t[ty + i2][tx] = src[(size_t)(r0 + ty + i2) * C + c0 + tx];
    __syncthreads();
    #pragma unroll
    for(int i2 = 0; i2 < 64; i2 += 4)
      dst[(size_t)(c0 + ty + i2) * 1024 + r0 + tx] = f2b(t[tx][ty + i2]);
  }
}

// ------------ shared GEMM core: C = A @ Bt^T, K=1024, BN=128, param BK -------
template<int BM, int BK>
DEVI void gemm_core(int mode, const u16* __restrict__ A, const u16* __restrict__ Bt,
                    const float* __restrict__ bias, void* __restrict__ Cp,
                    int m0, int n0, u16* sAb, u16* sBb){
  const int tid = threadIdx.x, w = tid >> 6, l = tid & 63;
  const int wr = w >> 1, wc = w & 1;
  constexpr int MI = BM / 32;
  constexpr int KK = BK / 32;
  constexpr int CPR = BK / 8;
  constexpr int CPT_A = BM * BK / 2048;
  constexpr int CPT_B = 128 * BK / 2048;
  constexpr int RB = 2 * BK;
  f32x4 acc[MI][4];
  #pragma unroll
  for(int a = 0; a < MI; a++)
    #pragma unroll
    for(int b = 0; b < 4; b++) acc[a][b] = (f32x4){0.f, 0.f, 0.f, 0.f};

  const int NT = 1024 / BK;
  auto STAGE = [&](int buf, int t){
    #pragma unroll
    for(int s2 = 0; s2 < CPT_A; s2++){
      int c = s2 * 256 + tid;
      int r = c / CPR, ch = (c % CPR) ^ (r & (CPR - 1));
      gload16((const char*)A + ((size_t)(m0 + r) * 1024 + t * BK) * 2 + ch * 16,
              (char*)sAb + (size_t)buf * BM * RB + c * 16);
    }
    #pragma unroll
    for(int s2 = 0; s2 < CPT_B; s2++){
      int c = s2 * 256 + tid;
      int r = c / CPR, ch = (c % CPR) ^ (r & (CPR - 1));
      gload16((const char*)Bt + ((size_t)(n0 + r) * 1024 + t * BK) * 2 + ch * 16,
              (char*)sBb + (size_t)buf * 128 * RB + c * 16);
    }
  };
  STAGE(0, 0);
  __syncthreads();
  for(int t = 0; t < NT; t++){
    const int cur = t & 1;
    if(t + 1 < NT) STAGE(cur ^ 1, t + 1);
    const char* pa = (const char*)sAb + (size_t)cur * BM * RB;
    const char* pb = (const char*)sBb + (size_t)cur * 128 * RB;
    s16x8 af[MI][KK], bf[4][KK];
    #pragma unroll
    for(int mi = 0; mi < MI; mi++){
      int r = (BM / 2) * wr + 16 * mi + (l & 15);
      #pragma unroll
      for(int kk = 0; kk < KK; kk++)
        af[mi][kk] = *(const s16x8*)(pa + r * RB +
                     ((kk * 64 + 16 * (l >> 4)) ^ ((r & (CPR - 1)) << 4)));
    }
    #pragma unroll
    for(int ni = 0; ni < 4; ni++){
      int r = 64 * wc + 16 * ni + (l & 15);
      #pragma unroll
      for(int kk = 0; kk < KK; kk++)
        bf[ni][kk] = *(const s16x8*)(pb + r * RB +
                     ((kk * 64 + 16 * (l >> 4)) ^ ((r & (CPR - 1)) << 4)));
    }
    #pragma unroll
    for(int kk = 0; kk < KK; kk++)
      #pragma unroll
      for(int mi = 0; mi < MI; mi++)
        #pragma unroll
        for(int ni = 0; ni < 4; ni++)
          acc[mi][ni] = MFMA(af[mi][kk], bf[ni][kk], acc[mi][ni]);
    __syncthreads();
  }
  #pragma unroll
  for(int mi = 0; mi < MI; mi++){
    #pragma unroll
    for(int ni = 0; ni < 4; ni++){
      #pragma unroll
      for(int i = 0; i < 4; i++){
        int gr = m0 + (BM / 2) * wr + 16 * mi + 4 * (l >> 4) + i;
        int gc = n0 + 64 * wc + 16 * ni + (l & 15);
        float v = acc[mi][ni][i];
        if(mode == 0){
          ((u16*)Cp)[(size_t)gr * 1024 + gc] = f2b(v + bias[gc]);
        } else if(mode == 1){
          ((u16*)Cp)[((size_t)(gc >> 10) << 20) + ((size_t)gr << 10) + (gc & 1023)] =
              f2b(v + bias[gr]);
        } else {
          ((float*)Cp)[(size_t)gr * 1024 + gc] = v + bias[gc];
        }
      }
    }
  }
}

// -------- K1: three projections, BK=32, 3 blocks/CU => all 768 resident ------
__global__ __launch_bounds__(256, 3)
void k_proj(const u16* __restrict__ Qb, const u16* __restrict__ Kb,
            const u16* __restrict__ Vb,
            const u16* __restrict__ WqT, const u16* __restrict__ WkT,
            const u16* __restrict__ WvT,
            const float* __restrict__ bq, const float* __restrict__ bk,
            const float* __restrict__ bv,
            u16* __restrict__ q_ws, u16* __restrict__ k_ws, u16* __restrict__ vT_ws){
  __shared__ u16 sA[2][128 * 32];
  __shared__ u16 sB[2][128 * 32];
  const int raw = blockIdx.x;
  const int bid = (raw & 7) * 96 + (raw >> 3);   // XCD-contiguous (768 % 8 == 0)
  if(bid < 256){
    gemm_core<128, 32>(0, Qb, WqT, bq, q_ws, (bid >> 3) * 128, (bid & 7) * 128,
                       &sA[0][0], &sB[0][0]);
  } else if(bid < 512){
    int b2 = bid - 256;
    gemm_core<128, 32>(0, Kb, WkT, bk, k_ws, (b2 >> 3) * 128, (b2 & 7) * 128,
                       &sA[0][0], &sB[0][0]);
  } else {
    int b2 = bid - 512;
    gemm_core<128, 32>(1, WvT, Vb, bv, vT_ws, (b2 >> 5) * 128, (b2 & 31) * 128,
                       &sA[0][0], &sB[0][0]);
  }
}

// ---------------- K3: output projection, BM=64/BK=64, XCD-swizzled -----------
__global__ __launch_bounds__(256)
void k_final(const u16* __restrict__ A, const u16* __restrict__ Bt,
             const float* __restrict__ bias, float* __restrict__ C){
  __shared__ u16 sA[2][64 * 64];
  __shared__ u16 sB[2][128 * 64];
  const int raw = blockIdx.x;
  const int bid = (raw & 7) * 64 + (raw >> 3);   // 512 % 8 == 0
  gemm_core<64, 64>(2, A, Bt, bias, C, (bid >> 3) * 64, (bid & 7) * 128,
                    &sA[0][0], &sB[0][0]);
}

// ---------------- K2: fused attention, single QK pass, P in registers --------
// Loop 1: K-staged QK^T + exp ONCE; P (bf16) packed into 128 VGPRs; rs summed.
// Loop 2: V-staged; unpack*inv -> attn fp32 stores + p_s transpose -> PV.
// 2 blocks/CU (VGPR ~210), 1024 blocks => 2 rounds => cross-block phase
// stagger (loop-1 of round-2 blocks overlaps loop-2 writes of round-1).
__global__ __launch_bounds__(256, 2)
void k_attn(const u16* __restrict__ qws, const u16* __restrict__ kws,
            const u16* __restrict__ vws, float* __restrict__ attn,
            u16* __restrict__ concat){
  __shared__ u16 k_s[2][64 * 64];   // 16 KB
  __shared__ u16 v_s[2][64 * 64];   // 16 KB
  __shared__ u16 p_s[64 * 64];      //  8 KB
  const int tid = threadIdx.x, w = tid >> 6, l = tid & 63;
  const int bx = blockIdx.x;
  const int bh = bx & 63, qb = bx >> 6, b = bh >> 4, h = bh & 15;
  const char* qg = (const char*)qws + ((size_t)(b * 1024 + qb * 64) * 1024 + h * 64) * 2;
  const char* kg = (const char*)kws + ((size_t)(b * 1024) * 1024 + h * 64) * 2;
  const char* vg = (const char*)vws + ((size_t)b * 1048576 + (size_t)h * 64 * 1024) * 2;
  float* ao = attn + (size_t)((h * 4 + b) * 1024 + qb * 64) * 1024;
  u16* cw = concat + (size_t)(b * 1024 + qb * 64) * 1024 + h * 64;

  auto STAGEK = [&](int buf, int kt){
    #pragma unroll
    for(int rd = 0; rd < 2; rd++){
      int c = rd * 256 + tid;
      int r = c >> 3, ch = c & 7;
      gload16(kg + (size_t)(kt * 64 + r) * 2048 + ((ch ^ (r & 7)) * 16),
              (char*)k_s[buf] + c * 16);
    }
  };
  auto STAGEV = [&](int buf, int kt){
    #pragma unroll
    for(int rd = 0; rd < 2; rd++){
      int c = rd * 256 + tid;
      int e = c >> 3, ch = c & 7;
      gload16(vg + (size_t)e * 2048 + kt * 128 + ((ch ^ (e & 7)) * 16),
              (char*)v_s[buf] + c * 16);
    }
  };

  // Q fragments straight to registers
  s16x8 af0, af1;
  {
    int rq = 16 * w + (l & 15);
    af0 = *(const s16x8*)(qg + (size_t)rq * 2048 + (l >> 4) * 16);
    af1 = *(const s16x8*)(qg + (size_t)rq * 2048 + 64 + (l >> 4) * 16);
  }

  const float KS = 0.18033688011112042f;  // log2(e)/8
  float rs[4] = {0.f, 0.f, 0.f, 0.f};
  uint32_t preg[16][8];                   // bf16(exp) pairs; ALL indices static

  // ---- loop 1: single QK^T pass, P -> registers, rs accumulated ----
  STAGEK(0, 0);
  __syncthreads();
  #pragma unroll
  for(int kt = 0; kt < 16; kt++){
    const int cur = kt & 1;
    if(kt + 1 < 16) STAGEK(cur ^ 1, kt + 1);
    #pragma unroll
    for(int f = 0; f < 4; f++){
      int r = 16 * f + (l & 15);
      s16x8 b0 = *(const s16x8*)((const char*)k_s[cur] + r * 128 + ((16 * (l >> 4)) ^ ((r & 7) << 4)));
      s16x8 b1 = *(const s16x8*)((const char*)k_s[cur] + r * 128 + ((64 + 16 * (l >> 4)) ^ ((r & 7) << 4)));
      f32x4 sf = (f32x4){0.f, 0.f, 0.f, 0.f};
      sf = MFMA(af0, b0, sf);
      sf = MFMA(af1, b1, sf);
      #pragma unroll
      for(int ip = 0; ip < 2; ip++){
        float e0 = exp2f(sf[2 * ip] * KS);
        float e1 = exp2f(sf[2 * ip + 1] * KS);
        rs[2 * ip] += e0;
        rs[2 * ip + 1] += e1;
        preg[kt][f * 2 + ip] = (uint32_t)f2b(e0) | ((uint32_t)f2b(e1) << 16);
      }
    }
    __syncthreads();
  }
  #pragma unroll
  for(int i = 0; i < 4; i++){
    #pragma unroll
    for(int m = 1; m < 16; m <<= 1) rs[i] += __shfl_xor(rs[i], m, 64);
  }
  float inv[4];
  #pragma unroll
  for(int i = 0; i < 4; i++) inv[i] = 1.0f / rs[i];

  f32x4 oacc[4];
  #pragma unroll
  for(int fe = 0; fe < 4; fe++) oacc[fe] = (f32x4){0.f, 0.f, 0.f, 0.f};

  // ---- loop 2: unpack*inv -> attn stores + p_s transpose -> PV ----
  STAGEV(0, 0);
  __syncthreads();
  #pragma unroll
  for(int kt = 0; kt < 16; kt++){
    const int cur = kt & 1;
    if(kt + 1 < 16) STAGEV(cur ^ 1, kt + 1);
    #pragma unroll
    for(int f = 0; f < 4; f++){
      #pragma unroll
      for(int ip = 0; ip < 2; ip++){
        uint32_t pk = preg[kt][f * 2 + ip];
        #pragma unroll
        for(int s = 0; s < 2; s++){
          int i = 2 * ip + s;
          float p = b2f((u16)((pk >> (16 * s)) & 0xffffu)) * inv[i];
          int rr = 16 * w + 4 * (l >> 4) + i;
          int cc = 16 * f + (l & 15);
          *(u16*)((char*)p_s + rr * 128 + ((cc * 2) ^ ((rr & 7) << 4))) = f2b(p);
          ao[(size_t)rr * 1024 + kt * 64 + cc] = p;
        }
      }
    }
    // PV
    #pragma unroll
    for(int kc = 0; kc < 2; kc++){
      int rp = 16 * w + (l & 15);
      s16x8 pa = *(const s16x8*)((const char*)p_s + rp * 128 +
                  ((kc * 64 + 16 * (l >> 4)) ^ ((rp & 7) << 4)));
      #pragma unroll
      for(int fe = 0; fe < 4; fe++){
        int e = 16 * fe + (l & 15);
        s16x8 bv = *(const s16x8*)((const char*)v_s[cur] + e * 128 +
                    ((kc * 64 + 16 * (l >> 4)) ^ ((e & 7) << 4)));
        oacc[fe] = MFMA(pa, bv, oacc[fe]);
      }
    }
    __syncthreads();
  }
  // concat epilogue
  #pragma unroll
  for(int fe = 0; fe < 4; fe++){
    #pragma unroll
    for(int i = 0; i < 4; i++){
      int qi = 16 * w + 4 * (l >> 4) + i;
      cw[(size_t)qi * 1024 + 16 * fe + (l & 15)] = f2b(oacc[fe][i]);
    }
  }
}

// ---------------- host launch ------------------------------------------------
extern "C" void kernel_launch(void* const* d_in, const int* in_sizes, int n_in,
                              void* d_out, int out_size, void* d_ws, size_t ws_size,
                              hipStream_t stream){
  const float* Q  = (const float*)d_in[0];
  const float* Kc = (const float*)d_in[1];
  const float* V  = (const float*)d_in[2];
  const float* Wq = (const float*)d_in[3];
  const float* bq = (const float*)d_in[4];
  const float* Wk = (const float*)d_in[5];
  const float* bk = (const float*)d_in[6];
  const float* Wv = (const float*)d_in[7];
  const float* bv = (const float*)d_in[8];
  const float* Wo = (const float*)d_in[9];
  const float* bo = (const float*)d_in[10];
  float* out = (float*)d_out;

  char* ws = (char*)d_ws;
  u16* q_ws      = (u16*)(ws + 0);         // [4096][1024] bf16
  u16* k_ws      = (u16*)(ws + 8388608);
  u16* vT_ws     = (u16*)(ws + 16777216);  // [b][h*64+e][1024]
  u16* concat_ws = (u16*)(ws + 25165824);
  u16* WqT = (u16*)(ws + 33554432);
  u16* WkT = (u16*)(ws + 35651584);
  u16* WvT = (u16*)(ws + 37748736);
  u16* WoT = (u16*)(ws + 39845888);

  // bf16 Q/K/V scratch in the not-yet-written attention region of d_out
  u16* Qb = (u16*)((char*)d_out + 16777216);
  u16* Kb = (u16*)((char*)d_out + 25165824);
  u16* Vb = (u16*)((char*)d_out + 33554432);
  float* attn = out + 4194304;

  k_prep<<<13312, 256, 0, stream>>>(Q, Kc, V, Qb, Kb, Vb,
                                    Wq, Wk, Wv, Wo, WqT, WkT, WvT, WoT);
  k_proj<<<768, 256, 0, stream>>>(Qb, Kb, Vb, WqT, WkT, WvT, bq, bk, bv,
                                  q_ws, k_ws, vT_ws);
  k_attn<<<1024, 256, 0, stream>>>(q_ws, k_ws, vT_ws, attn, concat_ws);
  k_final<<<512, 256, 0, stream>>>(concat_ws, WoT, bo, out);
}

// Round 13
// 187.293 us; speedup vs baseline: 1.1315x; 1.1315x over previous
//
#include <hip/hip_runtime.h>
#include <stdint.h>

#define DEVI __device__ __forceinline__
typedef unsigned short u16;
typedef __attribute__((ext_vector_type(8))) short s16x8;
typedef __attribute__((ext_vector_type(8))) unsigned short u16x8;
typedef __attribute__((ext_vector_type(4))) float f32x4;

typedef __attribute__((address_space(1))) void as1_void;
typedef __attribute__((address_space(3))) void as3_void;

DEVI u16 f2b(float f){
  union { float f; uint32_t u; } x; x.f = f;
  return (u16)((x.u + 0x7fffu + ((x.u >> 16) & 1u)) >> 16);
}
DEVI float b2f(u16 u){
  union { uint32_t u; float f; } x; x.u = ((uint32_t)u) << 16;
  return x.f;
}
DEVI void gload16(const void* g, void* l){
  __builtin_amdgcn_global_load_lds((as1_void*)g, (as3_void*)l, 16, 0, 0);
}
DEVI f32x4 MFMA(s16x8 a, s16x8 b, f32x4 c){
  return __builtin_amdgcn_mfma_f32_16x16x32_bf16(a, b, c, 0, 0, 0);
}

// ---------------- K0: weight transposes ONLY (1024 blocks, ~3 us) -----------
__global__ __launch_bounds__(256)
void k_prep(const float* __restrict__ Wq, const float* __restrict__ Wk,
            const float* __restrict__ Wv, const float* __restrict__ Wo,
            u16* __restrict__ WqT, u16* __restrict__ WkT,
            u16* __restrict__ WvT, u16* __restrict__ WoT){
  __shared__ float t[64][65];
  const int j = blockIdx.x, tid = threadIdx.x;
  const float* src; u16* dst; int C, r0, c0;
  if(j < 768){
    int tno = j >> 8, rem = j & 255, head = rem >> 4, rt = rem & 15;
    src = ((tno == 0) ? Wq : (tno == 1) ? Wk : Wv) + head * 65536;
    dst = ((tno == 0) ? WqT : (tno == 1) ? WkT : WvT) + head * 65536;
    C = 64; r0 = rt * 64; c0 = 0;
  } else {
    int j2 = j - 768;
    src = Wo; dst = WoT; C = 1024;
    r0 = (j2 & 15) * 64; c0 = (j2 >> 4) * 64;
  }
  int tx = tid & 63, ty = tid >> 6;
  #pragma unroll
  for(int i2 = 0; i2 < 64; i2 += 4)
    t[ty + i2][tx] = src[(size_t)(r0 + ty + i2) * C + c0 + tx];
  __syncthreads();
  #pragma unroll
  for(int i2 = 0; i2 < 64; i2 += 4)
    dst[(size_t)(c0 + ty + i2) * 1024 + r0 + tx] = f2b(t[tx][ty + i2]);
}

// ------- shared GEMM core: C = A @ Bt^T, K=1024, BN=128, fp32-or-bf16 ops ----
// AF32/BF32: operand is fp32 in global; converted to bf16 during reg-staging
// (load early / ds_write late, T14). bf16 operands use global_load_lds DMA.
// OMODE 0: bf16 out [M][1024], bias[col]
// OMODE 1: bf16 out at ((col>>10)<<20)+(row<<10)+(col&1023), bias[row]
// OMODE 2: fp32 out [M][1024], bias[col]
template<int BM, int BK, int OMODE, bool AF32, bool BF32>
DEVI void gemm_core(const void* __restrict__ Ap, const void* __restrict__ Btp,
                    const float* __restrict__ bias, void* __restrict__ Cp,
                    int m0, int n0, u16* sAb, u16* sBb){
  const int tid = threadIdx.x, w = tid >> 6, l = tid & 63;
  const int wr = w >> 1, wc = w & 1;
  constexpr int MI = BM / 32;
  constexpr int KK = BK / 32;
  constexpr int CPR = BK / 8;
  constexpr int CPT_A = BM * BK / 2048;
  constexpr int CPT_B = 128 * BK / 2048;
  constexpr int RB = 2 * BK;
  f32x4 acc[MI][4];
  #pragma unroll
  for(int a = 0; a < MI; a++)
    #pragma unroll
    for(int b = 0; b < 4; b++) acc[a][b] = (f32x4){0.f, 0.f, 0.f, 0.f};

  float4 la[AF32 ? CPT_A : 1][2];
  float4 lb[BF32 ? CPT_B : 1][2];

  auto LOADA = [&](int t){           // fp32 A: global -> regs
    if(AF32){
      #pragma unroll
      for(int s2 = 0; s2 < CPT_A; s2++){
        int c = s2 * 256 + tid;
        int r = c / CPR, ch = (c % CPR) ^ (r & (CPR - 1));
        const float* src = (const float*)Ap + (size_t)(m0 + r) * 1024 + t * BK + ch * 8;
        la[s2][0] = *(const float4*)src;
        la[s2][1] = *(const float4*)(src + 4);
      }
    }
  };
  auto LOADB = [&](int t){
    if(BF32){
      #pragma unroll
      for(int s2 = 0; s2 < CPT_B; s2++){
        int c = s2 * 256 + tid;
        int r = c / CPR, ch = (c % CPR) ^ (r & (CPR - 1));
        const float* src = (const float*)Btp + (size_t)(n0 + r) * 1024 + t * BK + ch * 8;
        lb[s2][0] = *(const float4*)src;
        lb[s2][1] = *(const float4*)(src + 4);
      }
    }
  };
  auto DMAA = [&](int buf, int t){   // bf16 A: global_load_lds
    if(!AF32){
      #pragma unroll
      for(int s2 = 0; s2 < CPT_A; s2++){
        int c = s2 * 256 + tid;
        int r = c / CPR, ch = (c % CPR) ^ (r & (CPR - 1));
        gload16((const char*)Ap + ((size_t)(m0 + r) * 1024 + t * BK) * 2 + ch * 16,
                (char*)sAb + (size_t)buf * BM * RB + c * 16);
      }
    }
  };
  auto DMAB = [&](int buf, int t){
    if(!BF32){
      #pragma unroll
      for(int s2 = 0; s2 < CPT_B; s2++){
        int c = s2 * 256 + tid;
        int r = c / CPR, ch = (c % CPR) ^ (r & (CPR - 1));
        gload16((const char*)Btp + ((size_t)(n0 + r) * 1024 + t * BK) * 2 + ch * 16,
                (char*)sBb + (size_t)buf * 128 * RB + c * 16);
      }
    }
  };
  auto WRITEA = [&](int buf){        // cvt + ds_write (after compute)
    if(AF32){
      #pragma unroll
      for(int s2 = 0; s2 < CPT_A; s2++){
        int c = s2 * 256 + tid;
        u16x8 o;
        #pragma unroll
        for(int jj = 0; jj < 4; jj++){
          o[jj]     = f2b(la[s2][0][jj]);
          o[4 + jj] = f2b(la[s2][1][jj]);
        }
        *(u16x8*)((char*)sAb + (size_t)buf * BM * RB + c * 16) = o;
      }
    }
  };
  auto WRITEB = [&](int buf){
    if(BF32){
      #pragma unroll
      for(int s2 = 0; s2 < CPT_B; s2++){
        int c = s2 * 256 + tid;
        u16x8 o;
        #pragma unroll
        for(int jj = 0; jj < 4; jj++){
          o[jj]     = f2b(lb[s2][0][jj]);
          o[4 + jj] = f2b(lb[s2][1][jj]);
        }
        *(u16x8*)((char*)sBb + (size_t)buf * 128 * RB + c * 16) = o;
      }
    }
  };

  const int NT = 1024 / BK;
  // prologue: stage tile 0
  LOADA(0); LOADB(0); DMAA(0, 0); DMAB(0, 0); WRITEA(0); WRITEB(0);
  __syncthreads();
  for(int t = 0; t < NT; t++){
    const int cur = t & 1;
    if(t + 1 < NT){ LOADA(t + 1); LOADB(t + 1); DMAA(cur ^ 1, t + 1); DMAB(cur ^ 1, t + 1); }
    const char* pa = (const char*)sAb + (size_t)cur * BM * RB;
    const char* pb = (const char*)sBb + (size_t)cur * 128 * RB;
    s16x8 af[MI][KK], bf[4][KK];
    #pragma unroll
    for(int mi = 0; mi < MI; mi++){
      int r = (BM / 2) * wr + 16 * mi + (l & 15);
      #pragma unroll
      for(int kk = 0; kk < KK; kk++)
        af[mi][kk] = *(const s16x8*)(pa + r * RB +
                     ((kk * 64 + 16 * (l >> 4)) ^ ((r & (CPR - 1)) << 4)));
    }
    #pragma unroll
    for(int ni = 0; ni < 4; ni++){
      int r = 64 * wc + 16 * ni + (l & 15);
      #pragma unroll
      for(int kk = 0; kk < KK; kk++)
        bf[ni][kk] = *(const s16x8*)(pb + r * RB +
                     ((kk * 64 + 16 * (l >> 4)) ^ ((r & (CPR - 1)) << 4)));
    }
    #pragma unroll
    for(int kk = 0; kk < KK; kk++)
      #pragma unroll
      for(int mi = 0; mi < MI; mi++)
        #pragma unroll
        for(int ni = 0; ni < 4; ni++)
          acc[mi][ni] = MFMA(af[mi][kk], bf[ni][kk], acc[mi][ni]);
    if(t + 1 < NT){ WRITEA(cur ^ 1); WRITEB(cur ^ 1); }
    __syncthreads();
  }
  #pragma unroll
  for(int mi = 0; mi < MI; mi++){
    #pragma unroll
    for(int ni = 0; ni < 4; ni++){
      #pragma unroll
      for(int i = 0; i < 4; i++){
        int gr = m0 + (BM / 2) * wr + 16 * mi + 4 * (l >> 4) + i;
        int gc = n0 + 64 * wc + 16 * ni + (l & 15);
        float v = acc[mi][ni][i];
        if(OMODE == 0){
          ((u16*)Cp)[(size_t)gr * 1024 + gc] = f2b(v + bias[gc]);
        } else if(OMODE == 1){
          ((u16*)Cp)[((size_t)(gc >> 10) << 20) + ((size_t)gr << 10) + (gc & 1023)] =
              f2b(v + bias[gr]);
        } else {
          ((float*)Cp)[(size_t)gr * 1024 + gc] = v + bias[gc];
        }
      }
    }
  }
}

// -------- K1: three projections reading fp32 Q/K/V directly ------------------
__global__ __launch_bounds__(256, 3)
void k_proj(const float* __restrict__ Q, const float* __restrict__ Kc,
            const float* __restrict__ V,
            const u16* __restrict__ WqT, const u16* __restrict__ WkT,
            const u16* __restrict__ WvT,
            const float* __restrict__ bq, const float* __restrict__ bk,
            const float* __restrict__ bv,
            u16* __restrict__ q_ws, u16* __restrict__ k_ws, u16* __restrict__ vT_ws){
  __shared__ u16 sA[2][128 * 32];
  __shared__ u16 sB[2][128 * 32];
  const int raw = blockIdx.x;
  const int bid = (raw & 7) * 96 + (raw >> 3);   // XCD-contiguous (768 % 8 == 0)
  if(bid < 256){
    gemm_core<128, 32, 0, true, false>(Q, WqT, bq, q_ws,
        (bid >> 3) * 128, (bid & 7) * 128, &sA[0][0], &sB[0][0]);
  } else if(bid < 512){
    int b2 = bid - 256;
    gemm_core<128, 32, 0, true, false>(Kc, WkT, bk, k_ws,
        (b2 >> 3) * 128, (b2 & 7) * 128, &sA[0][0], &sB[0][0]);
  } else {
    int b2 = bid - 512;
    gemm_core<128, 32, 1, false, true>(WvT, V, bv, vT_ws,
        (b2 >> 5) * 128, (b2 & 31) * 128, &sA[0][0], &sB[0][0]);
  }
}

// ---------------- K3: output projection, BM=64/BK=64, XCD-swizzled -----------
__global__ __launch_bounds__(256)
void k_final(const u16* __restrict__ A, const u16* __restrict__ Bt,
             const float* __restrict__ bias, float* __restrict__ C){
  __shared__ u16 sA[2][64 * 64];
  __shared__ u16 sB[2][128 * 64];
  const int raw = blockIdx.x;
  const int bid = (raw & 7) * 64 + (raw >> 3);   // 512 % 8 == 0
  gemm_core<64, 64, 2, false, false>(A, Bt, bias, C,
      (bid >> 3) * 64, (bid & 7) * 128, &sA[0][0], &sB[0][0]);
}

// ---------------- K2: fused attention (round-10 proven form) -----------------
__global__ __launch_bounds__(256, 4)
void k_attn(const u16* __restrict__ qws, const u16* __restrict__ kws,
            const u16* __restrict__ vws, float* __restrict__ attn,
            u16* __restrict__ concat){
  __shared__ u16 k_s[2][64 * 64];   // 16 KB
  __shared__ u16 v_s[2][64 * 64];   // 16 KB
  __shared__ u16 p_s[64 * 64];      //  8 KB
  const int tid = threadIdx.x, w = tid >> 6, l = tid & 63;
  const int bx = blockIdx.x;
  const int bh = bx & 63, qb = bx >> 6, b = bh >> 4, h = bh & 15;
  const char* qg = (const char*)qws + ((size_t)(b * 1024 + qb * 64) * 1024 + h * 64) * 2;
  const char* kg = (const char*)kws + ((size_t)(b * 1024) * 1024 + h * 64) * 2;
  const char* vg = (const char*)vws + ((size_t)b * 1048576 + (size_t)h * 64 * 1024) * 2;
  float* ao = attn + (size_t)((h * 4 + b) * 1024 + qb * 64) * 1024;
  u16* cw = concat + (size_t)(b * 1024 + qb * 64) * 1024 + h * 64;

  auto STAGEK = [&](int buf, int kt){
    #pragma unroll
    for(int rd = 0; rd < 2; rd++){
      int c = rd * 256 + tid;
      int r = c >> 3, ch = c & 7;
      gload16(kg + (size_t)(kt * 64 + r) * 2048 + ((ch ^ (r & 7)) * 16),
              (char*)k_s[buf] + c * 16);
    }
  };
  auto STAGEV = [&](int buf, int kt){
    #pragma unroll
    for(int rd = 0; rd < 2; rd++){
      int c = rd * 256 + tid;
      int e = c >> 3, ch = c & 7;
      gload16(vg + (size_t)e * 2048 + kt * 128 + ((ch ^ (e & 7)) * 16),
              (char*)v_s[buf] + c * 16);
    }
  };

  // Q fragments straight to registers
  s16x8 af0, af1;
  {
    int rq = 16 * w + (l & 15);
    af0 = *(const s16x8*)(qg + (size_t)rq * 2048 + (l >> 4) * 16);
    af1 = *(const s16x8*)(qg + (size_t)rq * 2048 + 64 + (l >> 4) * 16);
  }

  const float KS = 0.18033688011112042f;  // log2(e)/8
  float rs[4] = {0.f, 0.f, 0.f, 0.f};

  // ---- pass A: denominator sums ----
  STAGEK(0, 0);
  __syncthreads();
  for(int kt = 0; kt < 16; kt++){
    const int cur = kt & 1;
    if(kt + 1 < 16) STAGEK(cur ^ 1, kt + 1);
    #pragma unroll
    for(int f = 0; f < 4; f++){
      int r = 16 * f + (l & 15);
      s16x8 b0 = *(const s16x8*)((const char*)k_s[cur] + r * 128 + ((16 * (l >> 4)) ^ ((r & 7) << 4)));
      s16x8 b1 = *(const s16x8*)((const char*)k_s[cur] + r * 128 + ((64 + 16 * (l >> 4)) ^ ((r & 7) << 4)));
      f32x4 sf = (f32x4){0.f, 0.f, 0.f, 0.f};
      sf = MFMA(af0, b0, sf);
      sf = MFMA(af1, b1, sf);
      #pragma unroll
      for(int i = 0; i < 4; i++) rs[i] += exp2f(sf[i] * KS);
    }
    __syncthreads();
  }
  #pragma unroll
  for(int i = 0; i < 4; i++){
    #pragma unroll
    for(int m = 1; m < 16; m <<= 1) rs[i] += __shfl_xor(rs[i], m, 64);
  }
  float inv[4];
  #pragma unroll
  for(int i = 0; i < 4; i++) inv[i] = 1.0f / rs[i];

  f32x4 oacc[4];
  #pragma unroll
  for(int fe = 0; fe < 4; fe++) oacc[fe] = (f32x4){0.f, 0.f, 0.f, 0.f};

  // ---- pass B: QK -> P(normalized) -> p_s -> {PV, attn writeback} ----
  STAGEK(0, 0);
  STAGEV(0, 0);
  __syncthreads();
  for(int kt = 0; kt < 16; kt++){
    const int cur = kt & 1;
    if(kt + 1 < 16){ STAGEK(cur ^ 1, kt + 1); STAGEV(cur ^ 1, kt + 1); }
    f32x4 sf[4];
    #pragma unroll
    for(int f = 0; f < 4; f++){
      int r = 16 * f + (l & 15);
      s16x8 b0 = *(const s16x8*)((const char*)k_s[cur] + r * 128 + ((16 * (l >> 4)) ^ ((r & 7) << 4)));
      s16x8 b1 = *(const s16x8*)((const char*)k_s[cur] + r * 128 + ((64 + 16 * (l >> 4)) ^ ((r & 7) << 4)));
      sf[f] = (f32x4){0.f, 0.f, 0.f, 0.f};
      sf[f] = MFMA(af0, b0, sf[f]);
      sf[f] = MFMA(af1, b1, sf[f]);
    }
    #pragma unroll
    for(int f = 0; f < 4; f++){
      #pragma unroll
      for(int i = 0; i < 4; i++){
        float p = exp2f(sf[f][i] * KS) * inv[i];
        int rr = 16 * w + 4 * (l >> 4) + i;
        int cc = 16 * f + (l & 15);
        *(u16*)((char*)p_s + rr * 128 + ((cc * 2) ^ ((rr & 7) << 4))) = f2b(p);
      }
    }
    #pragma unroll
    for(int kc = 0; kc < 2; kc++){
      int rp = 16 * w + (l & 15);
      s16x8 pa = *(const s16x8*)((const char*)p_s + rp * 128 +
                  ((kc * 64 + 16 * (l >> 4)) ^ ((rp & 7) << 4)));
      #pragma unroll
      for(int fe = 0; fe < 4; fe++){
        int e = 16 * fe + (l & 15);
        s16x8 bv = *(const s16x8*)((const char*)v_s[cur] + e * 128 +
                    ((kc * 64 + 16 * (l >> 4)) ^ ((e & 7) << 4)));
        oacc[fe] = MFMA(pa, bv, oacc[fe]);
      }
    }
    // attn writeback: 16 lanes x f32x4 = one 256-B row segment (full sectors)
    #pragma unroll
    for(int it = 0; it < 4; it++){
      int row = 16 * w + 4 * it + (l >> 4);
      uint2 pv = *(const uint2*)((const char*)p_s + row * 128 +
                                 ((8 * (l & 15)) ^ ((row & 7) << 4)));
      f32x4 o;
      o[0] = b2f((u16)(pv.x & 0xffffu));
      o[1] = b2f((u16)(pv.x >> 16));
      o[2] = b2f((u16)(pv.y & 0xffffu));
      o[3] = b2f((u16)(pv.y >> 16));
      *(f32x4*)(ao + (size_t)row * 1024 + kt * 64 + (l & 15) * 4) = o;
    }
    __syncthreads();
  }
  // concat epilogue
  #pragma unroll
  for(int fe = 0; fe < 4; fe++){
    #pragma unroll
    for(int i = 0; i < 4; i++){
      int qi = 16 * w + 4 * (l >> 4) + i;
      cw[(size_t)qi * 1024 + 16 * fe + (l & 15)] = f2b(oacc[fe][i]);
    }
  }
}

// ---------------- host launch ------------------------------------------------
extern "C" void kernel_launch(void* const* d_in, const int* in_sizes, int n_in,
                              void* d_out, int out_size, void* d_ws, size_t ws_size,
                              hipStream_t stream){
  const float* Q  = (const float*)d_in[0];
  const float* Kc = (const float*)d_in[1];
  const float* V  = (const float*)d_in[2];
  const float* Wq = (const float*)d_in[3];
  const float* bq = (const float*)d_in[4];
  const float* Wk = (const float*)d_in[5];
  const float* bk = (const float*)d_in[6];
  const float* Wv = (const float*)d_in[7];
  const float* bv = (const float*)d_in[8];
  const float* Wo = (const float*)d_in[9];
  const float* bo = (const float*)d_in[10];
  float* out = (float*)d_out;

  char* ws = (char*)d_ws;
  u16* q_ws      = (u16*)(ws + 0);         // [4096][1024] bf16
  u16* k_ws      = (u16*)(ws + 8388608);
  u16* vT_ws     = (u16*)(ws + 16777216);  // [b][h*64+e][1024]
  u16* concat_ws = (u16*)(ws + 25165824);
  u16* WqT = (u16*)(ws + 33554432);
  u16* WkT = (u16*)(ws + 35651584);
  u16* WvT = (u16*)(ws + 37748736);
  u16* WoT = (u16*)(ws + 39845888);

  float* attn = out + 4194304;

  k_prep<<<1024, 256, 0, stream>>>(Wq, Wk, Wv, Wo, WqT, WkT, WvT, WoT);
  k_proj<<<768, 256, 0, stream>>>(Q, Kc, V, WqT, WkT, WvT, bq, bk, bv,
                                  q_ws, k_ws, vT_ws);
  k_attn<<<1024, 256, 0, stream>>>(q_ws, k_ws, vT_ws, attn, concat_ws);
  k_final<<<512, 256, 0, stream>>>(concat_ws, WoT, bo, out);
}

// Round 14
// 158.002 us; speedup vs baseline: 1.3412x; 1.1854x over previous
//
#include <hip/hip_runtime.h>
#include <stdint.h>

#define DEVI __device__ __forceinline__
typedef unsigned short u16;
typedef __attribute__((ext_vector_type(8))) short s16x8;
typedef __attribute__((ext_vector_type(4))) float f32x4;

typedef __attribute__((address_space(1))) void as1_void;
typedef __attribute__((address_space(3))) void as3_void;

DEVI u16 f2b(float f){
  union { float f; uint32_t u; } x; x.f = f;
  return (u16)((x.u + 0x7fffu + ((x.u >> 16) & 1u)) >> 16);
}
DEVI float b2f(u16 u){
  union { uint32_t u; float f; } x; x.u = ((uint32_t)u) << 16;
  return x.f;
}
DEVI void gload16(const void* g, void* l){
  __builtin_amdgcn_global_load_lds((as1_void*)g, (as3_void*)l, 16, 0, 0);
}
DEVI f32x4 MFMA(s16x8 a, s16x8 b, f32x4 c){
  return __builtin_amdgcn_mfma_f32_16x16x32_bf16(a, b, c, 0, 0, 0);
}

// ---------------- K0: all prep in ONE launch (R10 proven form) ---------------
__global__ __launch_bounds__(256)
void k_prep(const float* __restrict__ Q, const float* __restrict__ Kc,
            const float* __restrict__ V,
            u16* __restrict__ Qb, u16* __restrict__ Kb, u16* __restrict__ Vb,
            const float* __restrict__ Wq, const float* __restrict__ Wk,
            const float* __restrict__ Wv, const float* __restrict__ Wo,
            u16* __restrict__ WqT, u16* __restrict__ WkT,
            u16* __restrict__ WvT, u16* __restrict__ WoT){
  __shared__ float t[64][65];
  const int bid = blockIdx.x, tid = threadIdx.x;
  if(bid < 12288){
    int tno = bid >> 12;
    int blk = bid & 4095;
    const float* s = (tno == 0) ? Q : (tno == 1) ? Kc : V;
    u16* d = (tno == 0) ? Qb : (tno == 1) ? Kb : Vb;
    int i = (blk * 256 + tid) * 4;
    float4 v = *(const float4*)(s + i);
    ushort4 o;
    o.x = f2b(v.x); o.y = f2b(v.y); o.z = f2b(v.z); o.w = f2b(v.w);
    *(ushort4*)(d + i) = o;
  } else {
    int j = bid - 12288;
    const float* src; u16* dst; int C, r0, c0;
    if(j < 768){
      int tno = j >> 8, rem = j & 255, head = rem >> 4, rt = rem & 15;
      src = ((tno == 0) ? Wq : (tno == 1) ? Wk : Wv) + head * 65536;
      dst = ((tno == 0) ? WqT : (tno == 1) ? WkT : WvT) + head * 65536;
      C = 64; r0 = rt * 64; c0 = 0;
    } else {
      int j2 = j - 768;
      src = Wo; dst = WoT; C = 1024;
      r0 = (j2 & 15) * 64; c0 = (j2 >> 4) * 64;
    }
    int tx = tid & 63, ty = tid >> 6;
    #pragma unroll
    for(int i2 = 0; i2 < 64; i2 += 4)
      t[ty + i2][tx] = src[(size_t)(r0 + ty + i2) * C + c0 + tx];
    __syncthreads();
    #pragma unroll
    for(int i2 = 0; i2 < 64; i2 += 4)
      dst[(size_t)(c0 + ty + i2) * 1024 + r0 + tx] = f2b(t[tx][ty + i2]);
  }
}

// ------------ shared GEMM core: C = A @ Bt^T, K=1024, BN=128, param BK -------
template<int BM, int BK>
DEVI void gemm_core(int mode, const u16* __restrict__ A, const u16* __restrict__ Bt,
                    const float* __restrict__ bias, void* __restrict__ Cp,
                    int m0, int n0, u16* sAb, u16* sBb){
  const int tid = threadIdx.x, w = tid >> 6, l = tid & 63;
  const int wr = w >> 1, wc = w & 1;
  constexpr int MI = BM / 32;
  constexpr int KK = BK / 32;
  constexpr int CPR = BK / 8;
  constexpr int CPT_A = BM * BK / 2048;
  constexpr int CPT_B = 128 * BK / 2048;
  constexpr int RB = 2 * BK;
  f32x4 acc[MI][4];
  #pragma unroll
  for(int a = 0; a < MI; a++)
    #pragma unroll
    for(int b = 0; b < 4; b++) acc[a][b] = (f32x4){0.f, 0.f, 0.f, 0.f};

  const int NT = 1024 / BK;
  auto STAGE = [&](int buf, int t){
    #pragma unroll
    for(int s2 = 0; s2 < CPT_A; s2++){
      int c = s2 * 256 + tid;
      int r = c / CPR, ch = (c % CPR) ^ (r & (CPR - 1));
      gload16((const char*)A + ((size_t)(m0 + r) * 1024 + t * BK) * 2 + ch * 16,
              (char*)sAb + (size_t)buf * BM * RB + c * 16);
    }
    #pragma unroll
    for(int s2 = 0; s2 < CPT_B; s2++){
      int c = s2 * 256 + tid;
      int r = c / CPR, ch = (c % CPR) ^ (r & (CPR - 1));
      gload16((const char*)Bt + ((size_t)(n0 + r) * 1024 + t * BK) * 2 + ch * 16,
              (char*)sBb + (size_t)buf * 128 * RB + c * 16);
    }
  };
  STAGE(0, 0);
  __syncthreads();
  for(int t = 0; t < NT; t++){
    const int cur = t & 1;
    if(t + 1 < NT) STAGE(cur ^ 1, t + 1);
    const char* pa = (const char*)sAb + (size_t)cur * BM * RB;
    const char* pb = (const char*)sBb + (size_t)cur * 128 * RB;
    s16x8 af[MI][KK], bf[4][KK];
    #pragma unroll
    for(int mi = 0; mi < MI; mi++){
      int r = (BM / 2) * wr + 16 * mi + (l & 15);
      #pragma unroll
      for(int kk = 0; kk < KK; kk++)
        af[mi][kk] = *(const s16x8*)(pa + r * RB +
                     ((kk * 64 + 16 * (l >> 4)) ^ ((r & (CPR - 1)) << 4)));
    }
    #pragma unroll
    for(int ni = 0; ni < 4; ni++){
      int r = 64 * wc + 16 * ni + (l & 15);
      #pragma unroll
      for(int kk = 0; kk < KK; kk++)
        bf[ni][kk] = *(const s16x8*)(pb + r * RB +
                     ((kk * 64 + 16 * (l >> 4)) ^ ((r & (CPR - 1)) << 4)));
    }
    #pragma unroll
    for(int kk = 0; kk < KK; kk++)
      #pragma unroll
      for(int mi = 0; mi < MI; mi++)
        #pragma unroll
        for(int ni = 0; ni < 4; ni++)
          acc[mi][ni] = MFMA(af[mi][kk], bf[ni][kk], acc[mi][ni]);
    __syncthreads();
  }
  #pragma unroll
  for(int mi = 0; mi < MI; mi++){
    #pragma unroll
    for(int ni = 0; ni < 4; ni++){
      #pragma unroll
      for(int i = 0; i < 4; i++){
        int gr = m0 + (BM / 2) * wr + 16 * mi + 4 * (l >> 4) + i;
        int gc = n0 + 64 * wc + 16 * ni + (l & 15);
        float v = acc[mi][ni][i];
        if(mode == 0){
          ((u16*)Cp)[(size_t)gr * 1024 + gc] = f2b(v + bias[gc]);
        } else if(mode == 1){
          ((u16*)Cp)[((size_t)(gc >> 10) << 20) + ((size_t)gr << 10) + (gc & 1023)] =
              f2b(v + bias[gr]);
        } else {
          ((float*)Cp)[(size_t)gr * 1024 + gc] = v + bias[gc];
        }
      }
    }
  }
}

// -------- K1: three projections, BK=32, 3 blocks/CU => all 768 resident ------
__global__ __launch_bounds__(256, 3)
void k_proj(const u16* __restrict__ Qb, const u16* __restrict__ Kb,
            const u16* __restrict__ Vb,
            const u16* __restrict__ WqT, const u16* __restrict__ WkT,
            const u16* __restrict__ WvT,
            const float* __restrict__ bq, const float* __restrict__ bk,
            const float* __restrict__ bv,
            u16* __restrict__ q_ws, u16* __restrict__ k_ws, u16* __restrict__ vT_ws){
  __shared__ u16 sA[2][128 * 32];
  __shared__ u16 sB[2][128 * 32];
  const int raw = blockIdx.x;
  const int bid = (raw & 7) * 96 + (raw >> 3);   // XCD-contiguous (768 % 8 == 0)
  if(bid < 256){
    gemm_core<128, 32>(0, Qb, WqT, bq, q_ws, (bid >> 3) * 128, (bid & 7) * 128,
                       &sA[0][0], &sB[0][0]);
  } else if(bid < 512){
    int b2 = bid - 256;
    gemm_core<128, 32>(0, Kb, WkT, bk, k_ws, (b2 >> 3) * 128, (b2 & 7) * 128,
                       &sA[0][0], &sB[0][0]);
  } else {
    int b2 = bid - 512;
    gemm_core<128, 32>(1, WvT, Vb, bv, vT_ws, (b2 >> 5) * 128, (b2 & 31) * 128,
                       &sA[0][0], &sB[0][0]);
  }
}

// ---------------- K3: output projection, BM=64/BK=64, XCD-swizzled -----------
__global__ __launch_bounds__(256)
void k_final(const u16* __restrict__ A, const u16* __restrict__ Bt,
             const float* __restrict__ bias, float* __restrict__ C){
  __shared__ u16 sA[2][64 * 64];
  __shared__ u16 sB[2][128 * 64];
  const int raw = blockIdx.x;
  const int bid = (raw & 7) * 64 + (raw >> 3);   // 512 % 8 == 0
  gemm_core<64, 64>(2, A, Bt, bias, C, (bid >> 3) * 64, (bid & 7) * 128,
                    &sA[0][0], &sB[0][0]);
}

// ------- K2: fused attention, 8 waves / 128 q-rows per block, 48 KB LDS ------
// R10's proven two-pass structure; per-wave work identical, but K/V staging
// per q-row halves (1 chunk/thread) and per-tile barrier cost amortizes over
// 2x rows. 512 blocks = exactly 2/CU: single co-residency round, no tail.
__global__ __launch_bounds__(512, 2)
void k_attn(const u16* __restrict__ qws, const u16* __restrict__ kws,
            const u16* __restrict__ vws, float* __restrict__ attn,
            u16* __restrict__ concat){
  __shared__ u16 k_s[2][64 * 64];   // 16 KB
  __shared__ u16 v_s[2][64 * 64];   // 16 KB
  __shared__ u16 p_s[128 * 64];     // 16 KB
  const int tid = threadIdx.x, w = tid >> 6, l = tid & 63;
  const int bx = blockIdx.x;
  const int bh = bx & 63, qb = bx >> 6, b = bh >> 4, h = bh & 15;  // qb 0..7
  const char* qg = (const char*)qws + ((size_t)(b * 1024 + qb * 128) * 1024 + h * 64) * 2;
  const char* kg = (const char*)kws + ((size_t)(b * 1024) * 1024 + h * 64) * 2;
  const char* vg = (const char*)vws + ((size_t)b * 1048576 + (size_t)h * 64 * 1024) * 2;
  float* ao = attn + (size_t)((h * 4 + b) * 1024 + qb * 128) * 1024;
  u16* cw = concat + (size_t)(b * 1024 + qb * 128) * 1024 + h * 64;

  // 8 KB tile staged by 512 threads: exactly 1 chunk each
  auto STAGEK = [&](int buf, int kt){
    int r = tid >> 3, ch = tid & 7;
    gload16(kg + (size_t)(kt * 64 + r) * 2048 + ((ch ^ (r & 7)) * 16),
            (char*)k_s[buf] + tid * 16);
  };
  auto STAGEV = [&](int buf, int kt){
    int e = tid >> 3, ch = tid & 7;
    gload16(vg + (size_t)e * 2048 + kt * 128 + ((ch ^ (e & 7)) * 16),
            (char*)v_s[buf] + tid * 16);
  };

  // Q fragments straight to registers (wave w owns q-rows 16w..16w+15)
  s16x8 af0, af1;
  {
    int rq = 16 * w + (l & 15);
    af0 = *(const s16x8*)(qg + (size_t)rq * 2048 + (l >> 4) * 16);
    af1 = *(const s16x8*)(qg + (size_t)rq * 2048 + 64 + (l >> 4) * 16);
  }

  const float KS = 0.18033688011112042f;  // log2(e)/8
  float rs[4] = {0.f, 0.f, 0.f, 0.f};

  // ---- pass A: denominator sums ----
  STAGEK(0, 0);
  __syncthreads();
  for(int kt = 0; kt < 16; kt++){
    const int cur = kt & 1;
    if(kt + 1 < 16) STAGEK(cur ^ 1, kt + 1);
    #pragma unroll
    for(int f = 0; f < 4; f++){
      int r = 16 * f + (l & 15);
      s16x8 b0 = *(const s16x8*)((const char*)k_s[cur] + r * 128 + ((16 * (l >> 4)) ^ ((r & 7) << 4)));
      s16x8 b1 = *(const s16x8*)((const char*)k_s[cur] + r * 128 + ((64 + 16 * (l >> 4)) ^ ((r & 7) << 4)));
      f32x4 sf = (f32x4){0.f, 0.f, 0.f, 0.f};
      sf = MFMA(af0, b0, sf);
      sf = MFMA(af1, b1, sf);
      #pragma unroll
      for(int i = 0; i < 4; i++) rs[i] += exp2f(sf[i] * KS);
    }
    __syncthreads();
  }
  #pragma unroll
  for(int i = 0; i < 4; i++){
    #pragma unroll
    for(int m = 1; m < 16; m <<= 1) rs[i] += __shfl_xor(rs[i], m, 64);
  }
  float inv[4];
  #pragma unroll
  for(int i = 0; i < 4; i++) inv[i] = 1.0f / rs[i];

  f32x4 oacc[4];
  #pragma unroll
  for(int fe = 0; fe < 4; fe++) oacc[fe] = (f32x4){0.f, 0.f, 0.f, 0.f};

  // ---- pass B: QK -> P(normalized) -> p_s -> {PV, attn writeback} ----
  STAGEK(0, 0);
  STAGEV(0, 0);
  __syncthreads();
  for(int kt = 0; kt < 16; kt++){
    const int cur = kt & 1;
    if(kt + 1 < 16){ STAGEK(cur ^ 1, kt + 1); STAGEV(cur ^ 1, kt + 1); }
    f32x4 sf[4];
    #pragma unroll
    for(int f = 0; f < 4; f++){
      int r = 16 * f + (l & 15);
      s16x8 b0 = *(const s16x8*)((const char*)k_s[cur] + r * 128 + ((16 * (l >> 4)) ^ ((r & 7) << 4)));
      s16x8 b1 = *(const s16x8*)((const char*)k_s[cur] + r * 128 + ((64 + 16 * (l >> 4)) ^ ((r & 7) << 4)));
      sf[f] = (f32x4){0.f, 0.f, 0.f, 0.f};
      sf[f] = MFMA(af0, b0, sf[f]);
      sf[f] = MFMA(af1, b1, sf[f]);
    }
    // normalized P -> p_s (wave-private rows 16w..16w+15)
    #pragma unroll
    for(int f = 0; f < 4; f++){
      #pragma unroll
      for(int i = 0; i < 4; i++){
        float p = exp2f(sf[f][i] * KS) * inv[i];
        int rr = 16 * w + 4 * (l >> 4) + i;
        int cc = 16 * f + (l & 15);
        *(u16*)((char*)p_s + rr * 128 + ((cc * 2) ^ ((rr & 7) << 4))) = f2b(p);
      }
    }
    // PV: A-frags from p_s (own wave rows), B-frags from v_s
    #pragma unroll
    for(int kc = 0; kc < 2; kc++){
      int rp = 16 * w + (l & 15);
      s16x8 pa = *(const s16x8*)((const char*)p_s + rp * 128 +
                  ((kc * 64 + 16 * (l >> 4)) ^ ((rp & 7) << 4)));
      #pragma unroll
      for(int fe = 0; fe < 4; fe++){
        int e = 16 * fe + (l & 15);
        s16x8 bv = *(const s16x8*)((const char*)v_s[cur] + e * 128 +
                    ((kc * 64 + 16 * (l >> 4)) ^ ((e & 7) << 4)));
        oacc[fe] = MFMA(pa, bv, oacc[fe]);
      }
    }
    // attn writeback: 16 lanes x f32x4 = one 256-B row segment (full sectors)
    #pragma unroll
    for(int it = 0; it < 4; it++){
      int row = 16 * w + 4 * it + (l >> 4);
      uint2 pv = *(const uint2*)((const char*)p_s + row * 128 +
                                 ((8 * (l & 15)) ^ ((row & 7) << 4)));
      f32x4 o;
      o[0] = b2f((u16)(pv.x & 0xffffu));
      o[1] = b2f((u16)(pv.x >> 16));
      o[2] = b2f((u16)(pv.y & 0xffffu));
      o[3] = b2f((u16)(pv.y >> 16));
      *(f32x4*)(ao + (size_t)row * 1024 + kt * 64 + (l & 15) * 4) = o;
    }
    __syncthreads();
  }
  // concat epilogue
  #pragma unroll
  for(int fe = 0; fe < 4; fe++){
    #pragma unroll
    for(int i = 0; i < 4; i++){
      int qi = 16 * w + 4 * (l >> 4) + i;
      cw[(size_t)qi * 1024 + 16 * fe + (l & 15)] = f2b(oacc[fe][i]);
    }
  }
}

// ---------------- host launch ------------------------------------------------
extern "C" void kernel_launch(void* const* d_in, const int* in_sizes, int n_in,
                              void* d_out, int out_size, void* d_ws, size_t ws_size,
                              hipStream_t stream){
  const float* Q  = (const float*)d_in[0];
  const float* Kc = (const float*)d_in[1];
  const float* V  = (const float*)d_in[2];
  const float* Wq = (const float*)d_in[3];
  const float* bq = (const float*)d_in[4];
  const float* Wk = (const float*)d_in[5];
  const float* bk = (const float*)d_in[6];
  const float* Wv = (const float*)d_in[7];
  const float* bv = (const float*)d_in[8];
  const float* Wo = (const float*)d_in[9];
  const float* bo = (const float*)d_in[10];
  float* out = (float*)d_out;

  char* ws = (char*)d_ws;
  u16* q_ws      = (u16*)(ws + 0);         // [4096][1024] bf16
  u16* k_ws      = (u16*)(ws + 8388608);
  u16* vT_ws     = (u16*)(ws + 16777216);  // [b][h*64+e][1024]
  u16* concat_ws = (u16*)(ws + 25165824);
  u16* WqT = (u16*)(ws + 33554432);
  u16* WkT = (u16*)(ws + 35651584);
  u16* WvT = (u16*)(ws + 37748736);
  u16* WoT = (u16*)(ws + 39845888);

  // bf16 Q/K/V scratch in the not-yet-written attention region of d_out
  u16* Qb = (u16*)((char*)d_out + 16777216);
  u16* Kb = (u16*)((char*)d_out + 25165824);
  u16* Vb = (u16*)((char*)d_out + 33554432);
  float* attn = out + 4194304;

  k_prep<<<13312, 256, 0, stream>>>(Q, Kc, V, Qb, Kb, Vb,
                                    Wq, Wk, Wv, Wo, WqT, WkT, WvT, WoT);
  k_proj<<<768, 256, 0, stream>>>(Qb, Kb, Vb, WqT, WkT, WvT, bq, bk, bv,
                                  q_ws, k_ws, vT_ws);
  k_attn<<<512, 512, 0, stream>>>(q_ws, k_ws, vT_ws, attn, concat_ws);
  k_final<<<512, 256, 0, stream>>>(concat_ws, WoT, bo, out);
}